// Round 1
// baseline (122.038 us; speedup 1.0000x reference)
//
#include <hip/hip_runtime.h>
#include <hip/hip_bf16.h>
#include <stdint.h>

// Problem constants
#define BATCH 128
#define MAXN 1024
#define NF 9
#define DIM 256
#define TOTROWS 174

typedef uint32_t u32;
typedef __attribute__((ext_vector_type(8))) short bf16x8;
typedef __attribute__((ext_vector_type(4))) float f32x4;

__device__ __forceinline__ ushort f32_to_bf16_rne(float x) {
  u32 u = __float_as_uint(x);
  u += 0x7fffu + ((u >> 16) & 1u);
  return (ushort)(u >> 16);
}

// ---------------------------------------------------------------------------
// Prep kernel: grid = 256 blocks x 256 threads
//  blocks [0,128):   c[b][o] = lin_b[o] + sum_d W[o][256+d] * rxn_emb[cls_b][d]
//  blocks [128,192): convert W1 = lin_w[:, 0:256] -> bf16 row-major [o][k]
//  blocks [192,256): convert atom_emb (174x256 f32) -> bf16
// ---------------------------------------------------------------------------
__global__ __launch_bounds__(256) void prep_kernel(
    const int* __restrict__ rxn_class, const float* __restrict__ rxn_emb,
    const float* __restrict__ lin_w, const float* __restrict__ lin_b,
    const float* __restrict__ atom_emb,
    ushort* __restrict__ atomE, ushort* __restrict__ w1bf, float* __restrict__ cbuf)
{
  const int bid = blockIdx.x;
  const int t = threadIdx.x;
  if (bid < BATCH) {
    __shared__ float cls[DIM];
    cls[t] = rxn_emb[rxn_class[bid] * DIM + t];
    __syncthreads();
    float acc = lin_b[t];
    const float* wrow = lin_w + (size_t)t * 2 * DIM + DIM;  // W2 row o=t
#pragma unroll 4
    for (int d = 0; d < DIM; d += 4) {
      float4 w4 = *(const float4*)(wrow + d);
      acc += w4.x * cls[d] + w4.y * cls[d + 1] + w4.z * cls[d + 2] + w4.w * cls[d + 3];
    }
    cbuf[bid * DIM + t] = acc;
  } else if (bid < BATCH + 64) {
    // 65536 elems over 16384 threads -> 4 each
    int base = (bid - BATCH) * 256 + t;
    for (int i = base; i < DIM * DIM; i += 64 * 256) {
      int o = i >> 8, k = i & 255;
      w1bf[i] = f32_to_bf16_rne(lin_w[(size_t)o * 2 * DIM + k]);
    }
  } else {
    // 44544 elems over 16384 threads -> 3 each
    int base = (bid - BATCH - 64) * 256 + t;
    for (int i = base; i < TOTROWS * DIM; i += 64 * 256)
      atomE[i] = f32_to_bf16_rne(atom_emb[i]);
  }
}

// ---------------------------------------------------------------------------
// Main kernel: grid = 2048 blocks (64 nodes each) x 256 threads (4 waves).
// Wave w owns a 16-row node strip x all 256 output cols.
// A (enc) gathered into registers (f32 accumulate -> bf16 frags).
// B (W1, bf16 [o][k]) staged per 32-k chunk into LDS, 16B-granule XOR swizzle.
// out[m][o] = MFMA(enc, W1^T) + c[b][o]; masked rows give acc=0 -> out=c.
// ---------------------------------------------------------------------------
__global__ __launch_bounds__(256) void main_kernel(
    const int* __restrict__ node_feat, const int* __restrict__ num_nodes,
    const ushort* __restrict__ atomE, const ushort* __restrict__ w1bf,
    const float* __restrict__ cbuf, float* __restrict__ out)
{
  __shared__ uint4 bLds[1024];  // 16KB: [n=256][g=4] 16B granules, swizzled

  const int tid = threadIdx.x;
  const int lane = tid & 63;
  const int w = tid >> 6;
  const int blk = blockIdx.x;
  const int b = blk >> 4;                // 16 tiles of 64 nodes per batch
  const int node0 = (blk & 15) * 64;
  const int nn = num_nodes[b];
  const float* crow = cbuf + b * DIM;
  float* outb = out + (size_t)(b * MAXN) * DIM;

  if (node0 >= nn) {
    // fully masked tile: every row = c[b][:]
    float4 cv = *(const float4*)(crow + (tid & 63) * 4);
    for (int r = (tid >> 6); r < 64; r += 4)
      *(float4*)(outb + (size_t)(node0 + r) * DIM + (tid & 63) * 4) = cv;
    return;
  }

  const int r = lane & 15;   // A row / B col / D col within 16-tile
  const int g = lane >> 4;   // k-group
  const int node = node0 + w * 16 + r;
  const bool valid = node < nn;

  // --- gather enc -> A fragments (registers) ---
  const int OFF[NF] = {0, 119, 124, 136, 148, 158, 164, 170, 172};
  int idx[NF];
  const int* nfrow = node_feat + (size_t)(b * MAXN + node) * NF;
#pragma unroll
  for (int f = 0; f < NF; ++f) idx[f] = valid ? (nfrow[f] + OFF[f]) : 0;

  bf16x8 afrag[8];
#pragma unroll
  for (int kc = 0; kc < 8; ++kc) {
    const int k0 = kc * 32 + g * 8;
    float facc[8] = {0.f, 0.f, 0.f, 0.f, 0.f, 0.f, 0.f, 0.f};
    if (valid) {
#pragma unroll
      for (int f = 0; f < NF; ++f) {
        uint4 v = *(const uint4*)(atomE + idx[f] * DIM + k0);
        u32 p0 = v.x, p1 = v.y, p2 = v.z, p3 = v.w;
        facc[0] += __uint_as_float(p0 << 16);
        facc[1] += __uint_as_float(p0 & 0xffff0000u);
        facc[2] += __uint_as_float(p1 << 16);
        facc[3] += __uint_as_float(p1 & 0xffff0000u);
        facc[4] += __uint_as_float(p2 << 16);
        facc[5] += __uint_as_float(p2 & 0xffff0000u);
        facc[6] += __uint_as_float(p3 << 16);
        facc[7] += __uint_as_float(p3 & 0xffff0000u);
      }
    }
#pragma unroll
    for (int e = 0; e < 8; ++e) afrag[kc][e] = (short)f32_to_bf16_rne(facc[e]);
  }

  // --- MFMA main loop over k-chunks ---
  f32x4 acc[16];
#pragma unroll
  for (int nt = 0; nt < 16; ++nt) acc[nt] = (f32x4){0.f, 0.f, 0.f, 0.f};

  const int swz = g ^ ((r >> 1) & 3);  // read-side swizzle slot
  const int wnb = (tid >> 1) & 3;      // write-side swizzle

#pragma unroll
  for (int kc = 0; kc < 8; ++kc) {
    __syncthreads();
    {
      const uint4* src = (const uint4*)(w1bf + tid * DIM + kc * 32);
      uint4 v0 = src[0], v1 = src[1], v2 = src[2], v3 = src[3];
      bLds[tid * 4 + (0 ^ wnb)] = v0;
      bLds[tid * 4 + (1 ^ wnb)] = v1;
      bLds[tid * 4 + (2 ^ wnb)] = v2;
      bLds[tid * 4 + (3 ^ wnb)] = v3;
    }
    __syncthreads();
#pragma unroll
    for (int nt = 0; nt < 16; ++nt) {
      uint4 bv = bLds[(nt * 16 + r) * 4 + swz];
      bf16x8 bfrag = *reinterpret_cast<bf16x8*>(&bv);
      acc[nt] = __builtin_amdgcn_mfma_f32_16x16x32_bf16(afrag[kc], bfrag, acc[nt], 0, 0, 0);
    }
  }

  // --- epilogue: D layout col=lane&15, row=(lane>>4)*4+j (m89-verified) ---
  const int row0 = node0 + w * 16 + g * 4;
#pragma unroll
  for (int nt = 0; nt < 16; ++nt) {
    const int col = nt * 16 + r;
    const float cval = crow[col];
#pragma unroll
    for (int j = 0; j < 4; ++j)
      outb[(size_t)(row0 + j) * DIM + col] = acc[nt][j] + cval;
  }
}

extern "C" void kernel_launch(void* const* d_in, const int* in_sizes, int n_in,
                              void* d_out, int out_size, void* d_ws, size_t ws_size,
                              hipStream_t stream) {
  const int* node_feat = (const int*)d_in[0];
  const int* num_nodes = (const int*)d_in[1];
  const int* rxn_class = (const int*)d_in[2];
  const float* atom_emb = (const float*)d_in[3];
  const float* rxn_emb = (const float*)d_in[4];
  const float* lin_w = (const float*)d_in[5];
  const float* lin_b = (const float*)d_in[6];
  float* outp = (float*)d_out;

  // workspace layout (~344 KB): atomE bf16 | W1 bf16 | c f32
  ushort* atomE = (ushort*)d_ws;                                   // 174*256*2 = 89088
  ushort* w1bf = (ushort*)((char*)d_ws + 89088);                   // 256*256*2 = 131072
  float* cbuf = (float*)((char*)d_ws + 89088 + 131072);            // 128*256*4 = 131072

  prep_kernel<<<256, 256, 0, stream>>>(rxn_class, rxn_emb, lin_w, lin_b,
                                       atom_emb, atomE, w1bf, cbuf);
  main_kernel<<<2048, 256, 0, stream>>>(node_feat, num_nodes, atomE, w1bf, cbuf, outp);
}

// Round 2
// 73.589 us; speedup vs baseline: 1.6584x; 1.6584x over previous
//
#include <hip/hip_runtime.h>
#include <stdint.h>

#define BATCH 128
#define MAXN 1024
#define NF 9
#define DIM 256
#define TOTROWS 174

// ---------------------------------------------------------------------------
// Prep kernel, grid = 302 blocks x 256 threads:
//  blocks [0,128):   cbuf[b][o] = lin_b[o] + sum_d W2[o][d] * rxn_emb[cls_b][d]
//  blocks [128,302): P[r][o]    = sum_k atom_emb[r][k] * W1[o][k]
// (out[b,n,:] = sum_f P[idx_f] + cbuf[b] — the GEMM distributes over the
//  embedding sum, so the whole linear layer folds into the 174-row table.)
// ---------------------------------------------------------------------------
__global__ __launch_bounds__(256) void prep_kernel(
    const int* __restrict__ rxn_class, const float* __restrict__ rxn_emb,
    const float* __restrict__ lin_w, const float* __restrict__ lin_b,
    const float* __restrict__ atom_emb,
    float* __restrict__ P, float* __restrict__ cbuf)
{
  const int bid = blockIdx.x;
  const int t = threadIdx.x;
  if (bid < BATCH) {
    __shared__ float cls[DIM];
    cls[t] = rxn_emb[rxn_class[bid] * DIM + t];
    __syncthreads();
    float acc = lin_b[t];
    const float* wrow = lin_w + (size_t)t * 2 * DIM + DIM;  // W2 row o=t
#pragma unroll 4
    for (int d = 0; d < DIM; d += 4) {
      float4 w4 = *(const float4*)(wrow + d);
      acc += w4.x * cls[d] + w4.y * cls[d + 1] + w4.z * cls[d + 2] + w4.w * cls[d + 3];
    }
    cbuf[bid * DIM + t] = acc;
  } else {
    const int r = bid - BATCH;  // 0..173
    __shared__ float arow[DIM];
    arow[t] = atom_emb[r * DIM + t];
    __syncthreads();
    float acc = 0.f;
    const float* wrow = lin_w + (size_t)t * 2 * DIM;  // W1 row o=t
#pragma unroll 4
    for (int d = 0; d < DIM; d += 4) {
      float4 w4 = *(const float4*)(wrow + d);
      acc += w4.x * arow[d] + w4.y * arow[d + 1] + w4.z * arow[d + 2] + w4.w * arow[d + 3];
    }
    P[r * DIM + t] = acc;
  }
}

// ---------------------------------------------------------------------------
// Main kernel: grid = 2048 blocks x 256 threads (4 waves). One wave owns 16
// consecutive node slots of one batch. Per node: 9 wave-uniform-row gathers
// from P (1 KB each, uniform base + lane*16B -> perfectly coalesced), f32x4
// accumulate initialized to c[b], one float4 store. Masked nodes store c[b].
// No LDS, no barriers, no MFMA. ~60 VGPR -> 8 waves/SIMD, all waves resident.
// ---------------------------------------------------------------------------
__global__ __launch_bounds__(256) void main_kernel(
    const int* __restrict__ node_feat, const int* __restrict__ num_nodes,
    const float* __restrict__ P, const float* __restrict__ cbuf,
    float* __restrict__ out)
{
  const int tid = threadIdx.x;
  const int lane = tid & 63;
  const int wid = blockIdx.x * 4 + (tid >> 6);  // 0..8191
  const int b = wid >> 6;                       // 64 waves per batch
  const int n0 = (wid & 63) << 4;               // 16 nodes per wave
  const int nn = num_nodes[b];

  const float4 cf = *((const float4*)(cbuf + b * DIM) + lane);
  const float4* __restrict__ P4 = (const float4*)P;
  float4* __restrict__ out4 = (float4*)out + ((size_t)(b * MAXN + n0)) * 64 + lane;
  const int* __restrict__ nf = node_feat + (size_t)(b * MAXN + n0) * NF;

  const int OFF[NF] = {0, 119, 124, 136, 148, 158, 164, 170, 172};

#pragma unroll 2
  for (int i = 0; i < 16; ++i) {
    float4 acc = cf;
    if (n0 + i < nn) {
#pragma unroll
      for (int f = 0; f < NF; ++f) {
        const int row = nf[i * NF + f] + OFF[f];
        const float4 v = P4[row * 64 + lane];
        acc.x += v.x; acc.y += v.y; acc.z += v.z; acc.w += v.w;
      }
    }
    out4[i * 64] = acc;
  }
}

extern "C" void kernel_launch(void* const* d_in, const int* in_sizes, int n_in,
                              void* d_out, int out_size, void* d_ws, size_t ws_size,
                              hipStream_t stream) {
  const int* node_feat = (const int*)d_in[0];
  const int* num_nodes = (const int*)d_in[1];
  const int* rxn_class = (const int*)d_in[2];
  const float* atom_emb = (const float*)d_in[3];
  const float* rxn_emb = (const float*)d_in[4];
  const float* lin_w = (const float*)d_in[5];
  const float* lin_b = (const float*)d_in[6];
  float* outp = (float*)d_out;

  // workspace: P (174*256 f32 = 178176 B) | cbuf (128*256 f32 = 131072 B)
  float* P = (float*)d_ws;
  float* cbuf = (float*)((char*)d_ws + TOTROWS * DIM * sizeof(float));

  prep_kernel<<<BATCH + TOTROWS, 256, 0, stream>>>(rxn_class, rxn_emb, lin_w,
                                                   lin_b, atom_emb, P, cbuf);
  main_kernel<<<2048, 256, 0, stream>>>(node_feat, num_nodes, P, cbuf, outp);
}

// Round 3
// 59.610 us; speedup vs baseline: 2.0473x; 1.2345x over previous
//
#include <hip/hip_runtime.h>
#include <stdint.h>

#define BATCH 128
#define MAXN 1024
#define NF 9
#define DIM 256

// Combined-table layout (rows of 256 f32):
//  sec0: [0,119)    field0                          (119 rows)
//  sec1: [119,179)  fields1,2   idx = i1*12+i2      (60 rows)
//  sec2: [179,299)  fields3,4   idx = i3*10+i4      (120 rows)
//  sec3: [299,443)  fields5..8  idx = ((i5*6+i6)*2+i7)*2+i8  (144 rows)
#define BASE1 119
#define BASE2 179
#define BASE3 299
#define QROWS 443

// ---------------------------------------------------------------------------
// Prep: grid = 128 + 443 blocks x 256 threads.
//  bid<128: cbuf[b][o] = lin_b[o] + sum_d W2[o][d]*rxn_emb[cls_b][d]
//  else:    Q[q][o] = (sum of 1-4 atom_emb rows)[d] dot W1[o][d]
// (linear layer distributes over the embedding sum; field pairs pre-combined)
// ---------------------------------------------------------------------------
__global__ __launch_bounds__(256) void prep_kernel(
    const int* __restrict__ rxn_class, const float* __restrict__ rxn_emb,
    const float* __restrict__ lin_w, const float* __restrict__ lin_b,
    const float* __restrict__ atom_emb,
    float* __restrict__ Q, float* __restrict__ cbuf)
{
  const int bid = blockIdx.x;
  const int t = threadIdx.x;
  __shared__ float arow[DIM];

  if (bid < BATCH) {
    arow[t] = rxn_emb[rxn_class[bid] * DIM + t];
    __syncthreads();
    float acc = lin_b[t];
    const float* wrow = lin_w + (size_t)t * 2 * DIM + DIM;  // W2 row o=t
#pragma unroll 4
    for (int d = 0; d < DIM; d += 4) {
      float4 w4 = *(const float4*)(wrow + d);
      acc += w4.x * arow[d] + w4.y * arow[d + 1] + w4.z * arow[d + 2] + w4.w * arow[d + 3];
    }
    cbuf[bid * DIM + t] = acc;
    return;
  }

  const int q = bid - BATCH;
  float v;
  if (q < BASE1) {
    v = atom_emb[q * DIM + t];
  } else if (q < BASE2) {
    int q1 = q - BASE1, i1 = q1 / 12, i2 = q1 % 12;
    v = atom_emb[(119 + i1) * DIM + t] + atom_emb[(124 + i2) * DIM + t];
  } else if (q < BASE3) {
    int q2 = q - BASE2, i3 = q2 / 10, i4 = q2 % 10;
    v = atom_emb[(136 + i3) * DIM + t] + atom_emb[(148 + i4) * DIM + t];
  } else {
    int q3 = q - BASE3;
    int i8 = q3 & 1, i7 = (q3 >> 1) & 1, r = q3 >> 2, i6 = r % 6, i5 = r / 6;
    v = atom_emb[(158 + i5) * DIM + t] + atom_emb[(164 + i6) * DIM + t]
      + atom_emb[(170 + i7) * DIM + t] + atom_emb[(172 + i8) * DIM + t];
  }
  arow[t] = v;
  __syncthreads();
  float acc = 0.f;
  const float* wrow = lin_w + (size_t)t * 2 * DIM;  // W1 row o=t
#pragma unroll 4
  for (int d = 0; d < DIM; d += 4) {
    float4 w4 = *(const float4*)(wrow + d);
    acc += w4.x * arow[d] + w4.y * arow[d + 1] + w4.z * arow[d + 2] + w4.w * arow[d + 3];
  }
  Q[q * DIM + t] = acc;
}

// ---------------------------------------------------------------------------
// Main: grid = 2048 blocks x 256 threads (4 waves), wave = 16 node slots.
// All control state (wave id, batch, node base, nn, node_feat rows) is
// wave-uniform -> readfirstlane forces SGPR path: s_load indices, SALU index
// math, gathers are sgpr-base + lane*16B (1KB coalesced wave-gather from L2).
// Per valid node: 4 gathers + 16 v_add + 1 float4 store. Masked: store c[b].
// ---------------------------------------------------------------------------
__global__ __launch_bounds__(256) void main_kernel(
    const int* __restrict__ node_feat, const int* __restrict__ num_nodes,
    const float* __restrict__ Q, const float* __restrict__ cbuf,
    float* __restrict__ out)
{
  const int tid = threadIdx.x;
  const int lane = tid & 63;
  const int w = __builtin_amdgcn_readfirstlane(tid >> 6);
  const int wid = blockIdx.x * 4 + w;   // 0..8191
  const int b = wid >> 6;               // 64 waves per batch
  const int n0 = (wid & 63) << 4;       // 16 nodes per wave
  const int nn = num_nodes[b];

  const float4 cf = *((const float4*)(cbuf + b * DIM) + lane);
  float4* __restrict__ out4 = (float4*)out + ((size_t)(b * MAXN + n0)) * 64 + lane;

  if (n0 >= nn) {  // fully masked strip: pure broadcast store
#pragma unroll
    for (int i = 0; i < 16; ++i) out4[i * 64] = cf;
    return;
  }

  const int nv = (nn - n0 < 16) ? (nn - n0) : 16;  // wave-uniform
  const int* __restrict__ nfr = node_feat + (size_t)(b * MAXN + n0) * NF;
  const float4* __restrict__ Q4 = (const float4*)Q;

#pragma unroll 2
  for (int i = 0; i < 16; ++i) {
    float4 acc = cf;
    if (i < nv) {  // wave-uniform branch, no divergence
      const int* p = nfr + i * NF;
      const int j0 = p[0];
      const int j1 = BASE1 + p[1] * 12 + p[2];
      const int j2 = BASE2 + p[3] * 10 + p[4];
      const int j3 = BASE3 + ((p[5] * 6 + p[6]) * 2 + p[7]) * 2 + p[8];
      const float4 v0 = Q4[j0 * 64 + lane];
      const float4 v1 = Q4[j1 * 64 + lane];
      const float4 v2 = Q4[j2 * 64 + lane];
      const float4 v3 = Q4[j3 * 64 + lane];
      acc.x += (v0.x + v1.x) + (v2.x + v3.x);
      acc.y += (v0.y + v1.y) + (v2.y + v3.y);
      acc.z += (v0.z + v1.z) + (v2.z + v3.z);
      acc.w += (v0.w + v1.w) + (v2.w + v3.w);
    }
    out4[i * 64] = acc;
  }
}

extern "C" void kernel_launch(void* const* d_in, const int* in_sizes, int n_in,
                              void* d_out, int out_size, void* d_ws, size_t ws_size,
                              hipStream_t stream) {
  const int* node_feat = (const int*)d_in[0];
  const int* num_nodes = (const int*)d_in[1];
  const int* rxn_class = (const int*)d_in[2];
  const float* atom_emb = (const float*)d_in[3];
  const float* rxn_emb = (const float*)d_in[4];
  const float* lin_w = (const float*)d_in[5];
  const float* lin_b = (const float*)d_in[6];
  float* outp = (float*)d_out;

  // workspace: Q (443*256 f32 = 453632 B) | cbuf (128*256 f32 = 131072 B)
  float* Q = (float*)d_ws;
  float* cbuf = (float*)((char*)d_ws + QROWS * DIM * sizeof(float));

  prep_kernel<<<BATCH + QROWS, 256, 0, stream>>>(rxn_class, rxn_emb, lin_w,
                                                 lin_b, atom_emb, Q, cbuf);
  main_kernel<<<2048, 256, 0, stream>>>(node_feat, num_nodes, Q, cbuf, outp);
}

// Round 4
// 45.918 us; speedup vs baseline: 2.6578x; 1.2982x over previous
//
#include <hip/hip_runtime.h>
#include <stdint.h>

#define BATCH 128
#define MAXN 1024
#define NF 9
#define DIM 256
#define NCLS 10

// Combined-table layout (rows of 256 f32):
//  sec0: [0,119)    field0
//  sec1: [119,179)  fields1,2   idx = i1*12+i2
//  sec2: [179,299)  fields3,4   idx = i3*10+i4
//  sec3: [299,443)  fields5..8  idx = ((i5*6+i6)*2+i7)*2+i8
#define BASE1 119
#define BASE2 179
#define BASE3 299
#define QROWS 443

typedef __attribute__((ext_vector_type(4))) float f32x4;

// ---------------------------------------------------------------------------
// Prep: each block computes 4 table rows sharing one sweep over W rows.
//  bid in [0,3):    class rows: clsT[c][o] = lin_b[o] + sum_d W2[o][d]*rxn_emb[c][d]
//  bid in [3,114):  Q rows:     Q[q][o]    = sum_d W1[o][d]*S_q[d]
// where S_q = sum of 1-4 atom_emb rows (linear layer distributes over the
// embedding sum). 4 independent accumulators break the FMA dependency chain;
// W traffic is amortized 4x.
// ---------------------------------------------------------------------------
__global__ __launch_bounds__(256) void prep_kernel(
    const float* __restrict__ rxn_emb, const float* __restrict__ lin_w,
    const float* __restrict__ lin_b, const float* __restrict__ atom_emb,
    float* __restrict__ Q, float* __restrict__ clsT)
{
  __shared__ float S[4][DIM];
  const int bid = blockIdx.x;
  const int t = threadIdx.x;
  const bool isCls = bid < 3;
  const int row0 = isCls ? bid * 4 : (bid - 3) * 4;
  const int rmax = isCls ? NCLS : QROWS;
  const int nrows = (row0 + 4 <= rmax) ? 4 : (rmax - row0);

#pragma unroll
  for (int r = 0; r < 4; ++r) {
    float v = 0.f;
    if (r < nrows) {
      const int q = row0 + r;
      if (isCls) {
        v = rxn_emb[q * DIM + t];
      } else if (q < BASE1) {
        v = atom_emb[q * DIM + t];
      } else if (q < BASE2) {
        int x = q - BASE1;
        v = atom_emb[(119 + x / 12) * DIM + t] + atom_emb[(124 + x % 12) * DIM + t];
      } else if (q < BASE3) {
        int x = q - BASE2;
        v = atom_emb[(136 + x / 10) * DIM + t] + atom_emb[(148 + x % 10) * DIM + t];
      } else {
        int x = q - BASE3;
        int i8 = x & 1, i7 = (x >> 1) & 1, y = x >> 2;
        v = atom_emb[(158 + y / 6) * DIM + t] + atom_emb[(164 + y % 6) * DIM + t]
          + atom_emb[(170 + i7) * DIM + t] + atom_emb[(172 + i8) * DIM + t];
      }
    }
    S[r][t] = v;
  }
  __syncthreads();

  const float* wrow = lin_w + (size_t)t * 2 * DIM + (isCls ? DIM : 0);
  const float init = isCls ? lin_b[t] : 0.f;
  float a0 = init, a1 = init, a2 = init, a3 = init;
#pragma unroll 4
  for (int d = 0; d < DIM; d += 4) {
    float4 w4 = *(const float4*)(wrow + d);
    a0 += w4.x * S[0][d] + w4.y * S[0][d + 1] + w4.z * S[0][d + 2] + w4.w * S[0][d + 3];
    a1 += w4.x * S[1][d] + w4.y * S[1][d + 1] + w4.z * S[1][d + 2] + w4.w * S[1][d + 3];
    a2 += w4.x * S[2][d] + w4.y * S[2][d + 1] + w4.z * S[2][d + 2] + w4.w * S[2][d + 3];
    a3 += w4.x * S[3][d] + w4.y * S[3][d + 1] + w4.z * S[3][d + 2] + w4.w * S[3][d + 3];
  }
  float* dst = isCls ? clsT : Q;
  if (0 < nrows) dst[(row0 + 0) * DIM + t] = a0;
  if (1 < nrows) dst[(row0 + 1) * DIM + t] = a1;
  if (2 < nrows) dst[(row0 + 2) * DIM + t] = a2;
  if (3 < nrows) dst[(row0 + 3) * DIM + t] = a3;
}

// ---------------------------------------------------------------------------
// Main: 2048 blocks x 256 threads (4 waves); wave = 16 consecutive node slots.
// Three wave-uniform cases:
//  full strip:   straight-line 16 iters, no branches -> deep load pipelining
//  masked strip: 16 broadcast nt-stores of the class row
//  partial strip (<=1 wave/batch): branchless float-mask select (gathers are
//    always safe: node_feat holds valid categorical indices in ALL slots)
// Non-temporal stores keep the 134 MB output stream from thrashing Q out of L2.
// ---------------------------------------------------------------------------
__global__ __launch_bounds__(256, 4) void main_kernel(
    const int* __restrict__ node_feat, const int* __restrict__ num_nodes,
    const int* __restrict__ rxn_class,
    const float* __restrict__ Q, const float* __restrict__ clsT,
    float* __restrict__ out)
{
  const int tid = threadIdx.x;
  const int lane = tid & 63;
  const int w = __builtin_amdgcn_readfirstlane(tid >> 6);
  const int wid = blockIdx.x * 4 + w;   // 0..8191
  const int b = wid >> 6;               // 64 waves per batch
  const int n0 = (wid & 63) << 4;       // 16 nodes per wave
  const int nn = num_nodes[b];

  const f32x4 cf = ((const f32x4*)clsT)[rxn_class[b] * 64 + lane];
  f32x4* __restrict__ outp = (f32x4*)out + ((size_t)(b * MAXN + n0)) * 64 + lane;

  if (n0 >= nn) {  // fully masked strip
#pragma unroll
    for (int i = 0; i < 16; ++i)
      __builtin_nontemporal_store(cf, outp + i * 64);
    return;
  }

  const int* __restrict__ p = node_feat + (size_t)(b * MAXN + n0) * NF;
  const f32x4* __restrict__ Q4 = (const f32x4*)Q;

  if (n0 + 16 <= nn) {  // fully valid strip — branch-free body
#pragma unroll 4
    for (int i = 0; i < 16; ++i) {
      const int j0 = p[i * NF + 0];
      const int j1 = BASE1 + p[i * NF + 1] * 12 + p[i * NF + 2];
      const int j2 = BASE2 + p[i * NF + 3] * 10 + p[i * NF + 4];
      const int j3 = BASE3 + ((p[i * NF + 5] * 6 + p[i * NF + 6]) * 2 + p[i * NF + 7]) * 2 + p[i * NF + 8];
      const f32x4 v0 = Q4[j0 * 64 + lane];
      const f32x4 v1 = Q4[j1 * 64 + lane];
      const f32x4 v2 = Q4[j2 * 64 + lane];
      const f32x4 v3 = Q4[j3 * 64 + lane];
      const f32x4 s = (v0 + v1) + (v2 + v3);
      __builtin_nontemporal_store(cf + s, outp + i * 64);
    }
    return;
  }

  // partial strip: branchless mask
#pragma unroll 4
  for (int i = 0; i < 16; ++i) {
    const int j0 = p[i * NF + 0];
    const int j1 = BASE1 + p[i * NF + 1] * 12 + p[i * NF + 2];
    const int j2 = BASE2 + p[i * NF + 3] * 10 + p[i * NF + 4];
    const int j3 = BASE3 + ((p[i * NF + 5] * 6 + p[i * NF + 6]) * 2 + p[i * NF + 7]) * 2 + p[i * NF + 8];
    const f32x4 v0 = Q4[j0 * 64 + lane];
    const f32x4 v1 = Q4[j1 * 64 + lane];
    const f32x4 v2 = Q4[j2 * 64 + lane];
    const f32x4 v3 = Q4[j3 * 64 + lane];
    const float m = (n0 + i < nn) ? 1.f : 0.f;
    const f32x4 s = (v0 + v1) + (v2 + v3);
    __builtin_nontemporal_store(cf + m * s, outp + i * 64);
  }
}

extern "C" void kernel_launch(void* const* d_in, const int* in_sizes, int n_in,
                              void* d_out, int out_size, void* d_ws, size_t ws_size,
                              hipStream_t stream) {
  const int* node_feat = (const int*)d_in[0];
  const int* num_nodes = (const int*)d_in[1];
  const int* rxn_class = (const int*)d_in[2];
  const float* atom_emb = (const float*)d_in[3];
  const float* rxn_emb = (const float*)d_in[4];
  const float* lin_w = (const float*)d_in[5];
  const float* lin_b = (const float*)d_in[6];
  float* outp = (float*)d_out;

  // workspace: Q (443*256 f32 = 453632 B) | clsT (10*256 f32 = 10240 B)
  float* Q = (float*)d_ws;
  float* clsT = (float*)((char*)d_ws + QROWS * DIM * sizeof(float));

  const int nQblocks = (QROWS + 3) / 4;  // 111
  prep_kernel<<<3 + nQblocks, 256, 0, stream>>>(rxn_emb, lin_w, lin_b,
                                                atom_emb, Q, clsT);
  main_kernel<<<2048, 256, 0, stream>>>(node_feat, num_nodes, rxn_class,
                                        Q, clsT, outp);
}